// Round 3
// baseline (403.343 us; speedup 1.0000x reference)
//
#include <hip/hip_runtime.h>
#include <hip/hip_bf16.h>

// Problem: out[n,o] = x[n,:] . W[o,:] + bias[o] + scale * sum_r (x[n,:].la[a,r,:]) * lb[a,o,:][r]
//          where a = lora_mapping[n]-1 (skip if mapping==0).
// Strategy: fold LoRA into the GEMM K-dim. Build bf16 Xe[16384,2176], We[2048,2176]
//   Xe[:,0:2048]=bf16(x); Xe[n,2048+(a*16+r)] = bf16(scale * x[n].la[a,r])  (one-hot in a)
//   We[:,0:2048]=bf16(W); We[o,2048+(a*16+r)] = bf16(lb[a,o,r])
// Then out = Xe @ We^T + bias — a single uniform bf16 MFMA GEMM, K=2176=34*64.
//
// R1: prep_x scalar+shuffle latency-bound (154us).
// R2 FAILED: 16 parallel accumulators spilled -> 231us.
// R3: u via MFMA all-adapters, mask in epilogue. 456us.
// R4 NEUTRAL: split prep into conv/ext kernels -> 464us.
// R5: conv_prep (all conversions, one pass) + ext_gemm (skinny LDS GEMM). 400us.
//   gemm_fused 147us -> prep chain ~253us by subtraction, ~4x over roofline.
// R6 (this round):
//   - conv_prep: grid-stride while-loop prevented unrolling -> ~1 load in
//     flight/lane (the ~1TB/s signature). Exact-trip: 2336 blocks x 256 thr x
//     exactly 8 units, fully unrolled, 16 loads issued before any store.
//   - ext_gemm: was staging-latency-bound (32 barrier-drained K-steps, 8 MFMA
//     each). Now BK=128, double-buffered LDS (80KB, 2 blk/CU), 2-phase:
//     STAGE(kt+1) issued before compute(kt), one syncthreads/tile.
//   - gemm_fused untouched (993 TF effective; 256^2 8-phase is next).

#define D_IN   2048
#define D_OUT  2048
#define NTOK   16384
#define RANK   16
#define NADAPT 8
#define KEXT   2176          // 2048 + 8*16
#define BM     128
#define BN     128
#define BK     64
#define EBM    32            // ext_gemm M-tile
#define EBK    128           // ext_gemm K-tile

typedef __attribute__((ext_vector_type(8))) __bf16 bf16x8;
typedef __attribute__((ext_vector_type(8))) unsigned short u16x8;
typedef __attribute__((ext_vector_type(4))) float  f32x4;

__device__ inline unsigned short f2bf(float f) {
    unsigned u = __builtin_bit_cast(unsigned, f);
    u += 0x7fffu + ((u >> 16) & 1u);      // round-to-nearest-even
    return (unsigned short)(u >> 16);
}

// ---------------------------------------------------------------------------
// conv_prep: one pass for every fp32->bf16 conversion. Unit = 8 contiguous
// elements (32B read, 16B write), all 16B-aligned:
//   seg0: x[16384][2048]  -> Xe base cols (KEXT row stride)
//   seg1: W[2048][2048]   -> We base cols
//   seg2: la[8][16][2048] -> La[128][2048] (contiguous)
//   seg3: lb[8][2048][16] -> We ext cols (unit of 8 ext cols = 8 contiguous
//         source floats lb[(a*2048+o)*16 + r .. +7], a=m>>1, r=(m&1)*8)
// TOTU = 4,784,128 = 2336 blocks * 256 threads * 8 units exactly.
// Fully unrolled: all 16 dwordx4 loads in flight before the stores.
// ---------------------------------------------------------------------------
#define SEG0 ((size_t)NTOK * 256)            // 4194304 units of x
#define SEG1 (SEG0 + (size_t)D_OUT * 256)    // + 524288 units of W
#define SEG2 (SEG1 + 32768)                  // + la units (8*16*2048/8)
#define TOTU (SEG2 + 32768)                  // + lb-ext units (2048*128/8)
#define CONV_SPAN 598016                     // units per j-step = 2336*256

__global__ void conv_prep(const float* __restrict__ x, const float* __restrict__ w,
                          const float* __restrict__ la, const float* __restrict__ lb,
                          unsigned short* __restrict__ Xe, unsigned short* __restrict__ We,
                          unsigned short* __restrict__ La) {
    size_t gid = (size_t)blockIdx.x * 256 + threadIdx.x;   // < 598016
    float4 v0[8], v1[8];
    unsigned short* dst[8];
#pragma unroll
    for (int j = 0; j < 8; ++j) {
        size_t u = (size_t)j * CONV_SPAN + gid;
        const float* src;
        unsigned short* d;
        if (u < SEG0) {
            int n = (int)(u >> 8), kc = ((int)u & 255) * 8;
            src = x + (size_t)n * D_IN + kc;
            d   = Xe + (size_t)n * KEXT + kc;
        } else if (u < SEG1) {
            size_t v = u - SEG0;
            int o = (int)(v >> 8), kc = ((int)v & 255) * 8;
            src = w + (size_t)o * D_IN + kc;
            d   = We + (size_t)o * KEXT + kc;
        } else if (u < SEG2) {
            size_t v = u - SEG1;
            src = la + v * 8;
            d   = La + v * 8;
        } else {
            size_t v = u - SEG2;
            int o = (int)(v >> 4), m = (int)v & 15;
            int a = m >> 1, r = (m & 1) * 8;
            src = lb + ((size_t)a * D_OUT + o) * RANK + r;
            d   = We + (size_t)o * KEXT + D_IN + m * 8;
        }
        v0[j] = *(const float4*)(src);
        v1[j] = *(const float4*)(src + 4);
        dst[j] = d;
    }
#pragma unroll
    for (int j = 0; j < 8; ++j) {
        u16x8 s;
        s[0] = f2bf(v0[j].x); s[1] = f2bf(v0[j].y); s[2] = f2bf(v0[j].z); s[3] = f2bf(v0[j].w);
        s[4] = f2bf(v1[j].x); s[5] = f2bf(v1[j].y); s[6] = f2bf(v1[j].z); s[7] = f2bf(v1[j].w);
        *(u16x8*)dst[j] = s;
    }
}

// ---------------------------------------------------------------------------
// ext_gemm: u[n][c] = Xb[n,:] . La[c,:], n in 32-token tiles, c = 0..127.
// BM=32, BN=128, BK=128, 4 waves; wave w owns cols w*32..+31 (adapters 2w,
// 2w+1 -> mask/scale wave-uniform). Double-buffered LDS (80 KB, 2 blk/CU),
// 2-phase pipeline: STAGE(kt+1) issued before compute(kt); the single
// __syncthreads per tile drains vmcnt+lgkm (compiler semantics), so staging
// latency overlaps the 16 MFMAs + ds_reads of the current tile.
// global_load_lds w=16 with XOR-swizzled SOURCE chunk (gc = kc ^ (row&7)),
// linear LDS dest (wave-uniform base + lane*16 requirement); ds_read applies
// the same XOR -> 2-way banks max.
// u C-layout: col=lane&15 (ext col), row=(lane>>4)*4+reg (token) [m89-verified].
// Reads Xe base cols / writes ext cols: disjoint, no hazard.
// ---------------------------------------------------------------------------
__global__ void ext_gemm(unsigned short* Xe, const int* __restrict__ map,
                         const unsigned short* __restrict__ La,
                         const float* __restrict__ scaling) {
    __shared__ unsigned short As[2][EBM * EBK];          // 2 x 8 KB
    __shared__ unsigned short Bs[2][128 * EBK];          // 2 x 32 KB

    int t = threadIdx.x, lane = t & 63, wave = t >> 6;
    int n0 = blockIdx.x * EBM;

    f32x4 acc[2][2] = {};

    auto stage = [&](int buf, int kt) {
        int k0 = kt * EBK;
#pragma unroll
        for (int c = 0; c < 2; ++c) {                    // A: 512 chunks, 2/thread
            int linear = (wave * 2 + c) * 64 + lane;
            int row = linear >> 4, kc = linear & 15;
            int gc = kc ^ (row & 7);
            const unsigned short* ga = Xe + (size_t)(n0 + row) * KEXT + k0 + gc * 8;
            __builtin_amdgcn_global_load_lds(
                (const __attribute__((address_space(1))) unsigned int*)ga,
                (__attribute__((address_space(3))) unsigned int*)(&As[buf][0] + (wave * 2 + c) * 512),
                16, 0, 0);
        }
#pragma unroll
        for (int c = 0; c < 8; ++c) {                    // B: 2048 chunks, 8/thread
            int linear = (wave * 8 + c) * 64 + lane;
            int row = linear >> 4, kc = linear & 15;
            int gc = kc ^ (row & 7);
            const unsigned short* gb = La + (size_t)row * D_IN + k0 + gc * 8;
            __builtin_amdgcn_global_load_lds(
                (const __attribute__((address_space(1))) unsigned int*)gb,
                (__attribute__((address_space(3))) unsigned int*)(&Bs[buf][0] + (wave * 8 + c) * 512),
                16, 0, 0);
        }
    };

    auto compute = [&](int buf) {
#pragma unroll
        for (int ks = 0; ks < 4; ++ks) {                 // four K=32 steps
            int gchunk = ks * 4 + (lane >> 4);
            int sw = gchunk ^ (lane & 7);                // row&7 == lane&7 (16-aligned tiles)
            bf16x8 af[2], bfr[2];
#pragma unroll
            for (int i = 0; i < 2; ++i)
                af[i] = *(const bf16x8*)(&As[buf][(i * 16 + (lane & 15)) * EBK + sw * 8]);
#pragma unroll
            for (int j = 0; j < 2; ++j)
                bfr[j] = *(const bf16x8*)(&Bs[buf][(wave * 32 + j * 16 + (lane & 15)) * EBK + sw * 8]);
#pragma unroll
            for (int i = 0; i < 2; ++i)
#pragma unroll
                for (int j = 0; j < 2; ++j)
                    acc[i][j] = __builtin_amdgcn_mfma_f32_16x16x32_bf16(af[i], bfr[j], acc[i][j], 0, 0, 0);
        }
    };

    stage(0, 0);
    __syncthreads();                                     // drains vmcnt -> buf0 ready
    int cur = 0;
    for (int kt = 0; kt < D_IN / EBK; ++kt) {            // 16 K-tiles
        if (kt + 1 < D_IN / EBK) stage(cur ^ 1, kt + 1); // prefetch next tile
        compute(cur);                                    // overlap with stage latency
        __syncthreads();                                 // drain vmcnt; readers done
        cur ^= 1;
    }

    // epilogue: c = wave*32 + j*16 + (lane&15) -> adapter a = wave*2 + j (uniform)
    int colq = lane & 15, rq = lane >> 4;
#pragma unroll
    for (int j = 0; j < 2; ++j) {
        int c = wave * 32 + j * 16 + colq;
        int aid = wave * 2 + j + 1;
        float sc = scaling[wave * 2 + j];
#pragma unroll
        for (int i = 0; i < 2; ++i) {
#pragma unroll
            for (int r = 0; r < 4; ++r) {
                int token = n0 + i * 16 + rq * 4 + r;
                unsigned short v = 0;
                if (map[token] == aid) v = f2bf(acc[i][j][r] * sc);
                Xe[(size_t)token * KEXT + D_IN + c] = v;
            }
        }
    }
}

// ---------------------------------------------------------------------------
// Main GEMM: out[M=16384, N=2048] = Xe @ We^T + bias.  m97 structure:
// 128x128 tile, BK=64, 4 waves in 2x2, each wave 64x64 via 4x4 of 16x16x32
// bf16 MFMA, global_load_lds width=16 staging, XOR-swizzled LDS k-chunks
// (swizzle applied on the global source address so the wave-uniform LDS
// destination stays contiguous — required by global_load_lds semantics).
// ---------------------------------------------------------------------------
__global__ void gemm_fused(const unsigned short* __restrict__ Xe,
                           const unsigned short* __restrict__ We,
                           const float* __restrict__ bias,
                           float* __restrict__ out) {
    __shared__ unsigned short As[BM * BK];               // [128][64] bf16, 16 KB
    __shared__ unsigned short Bs[BN * BK];

    int t = threadIdx.x;
    int lane = t & 63, wave = t >> 6;
    // supertile swizzle: groups of 8 row-tiles x 16 col-tiles for L2 locality
    int g = blockIdx.x;
    int group = g >> 7, within = g & 127;
    int bm = group * 8 + (within & 7);                   // 0..127
    int bn = within >> 3;                                // 0..15

    int wm = wave >> 1, wn = wave & 1;                   // 2x2 wave grid
    f32x4 acc[4][4] = {};

    for (int k0 = 0; k0 < KEXT; k0 += BK) {
        __syncthreads();                                 // prev compute done
#pragma unroll
        for (int c = 0; c < 4; ++c) {
            int linear = (wave * 4 + c) * 64 + lane;     // 16B-chunk id within tile
            int row = linear >> 3;                       // 0..127
            int kc  = linear & 7;                        // 16B chunk within row
            int gc  = kc ^ (row & 7);                    // fetch swizzled source chunk
            const unsigned short* ga = Xe + (size_t)(bm * BM + row) * KEXT + k0 + gc * 8;
            __builtin_amdgcn_global_load_lds(
                (const __attribute__((address_space(1))) unsigned int*)ga,
                (__attribute__((address_space(3))) unsigned int*)(As + (wave * 4 + c) * 512),
                16, 0, 0);
            const unsigned short* gb = We + (size_t)(bn * BN + row) * KEXT + k0 + gc * 8;
            __builtin_amdgcn_global_load_lds(
                (const __attribute__((address_space(1))) unsigned int*)gb,
                (__attribute__((address_space(3))) unsigned int*)(Bs + (wave * 4 + c) * 512),
                16, 0, 0);
        }
        __syncthreads();                                 // staging visible (compiler drains vmcnt)
#pragma unroll
        for (int ks = 0; ks < 2; ++ks) {                 // two K=32 steps per BK=64
            bf16x8 af[4], bfr[4];
            int gchunk = ks * 4 + (lane >> 4);
            int sw = gchunk ^ (lane & 7);                // row&7 == lane&7 for 16-aligned tiles
#pragma unroll
            for (int i = 0; i < 4; ++i) {
                int rowA = wm * 64 + i * 16 + (lane & 15);
                af[i]  = *(const bf16x8*)(As + rowA * BK + sw * 8);
                int rowB = wn * 64 + i * 16 + (lane & 15);
                bfr[i] = *(const bf16x8*)(Bs + rowB * BK + sw * 8);
            }
#pragma unroll
            for (int i = 0; i < 4; ++i)
#pragma unroll
                for (int j = 0; j < 4; ++j)
                    acc[i][j] = __builtin_amdgcn_mfma_f32_16x16x32_bf16(af[i], bfr[j], acc[i][j], 0, 0, 0);
        }
    }

    // epilogue: C/D layout col=lane&15, row=(lane>>4)*4+reg  [m89-verified]
    int colq = lane & 15, rq = lane >> 4;
#pragma unroll
    for (int j = 0; j < 4; ++j) {
        int col = bn * BN + wn * 64 + j * 16 + colq;
        float bv = bias[col];
#pragma unroll
        for (int i = 0; i < 4; ++i) {
            int row0 = bm * BM + wm * 64 + i * 16 + rq * 4;
#pragma unroll
            for (int r = 0; r < 4; ++r)
                out[(size_t)(row0 + r) * D_OUT + col] = acc[i][j][r] + bv;
        }
    }
}

extern "C" void kernel_launch(void* const* d_in, const int* in_sizes, int n_in,
                              void* d_out, int out_size, void* d_ws, size_t ws_size,
                              hipStream_t stream) {
    (void)in_sizes; (void)n_in; (void)out_size; (void)ws_size;
    const float* x       = (const float*)d_in[0];
    const int*   map     = (const int*)d_in[1];
    const float* weight  = (const float*)d_in[2];
    const float* bias    = (const float*)d_in[3];
    const float* lora_a  = (const float*)d_in[4];
    const float* lora_b  = (const float*)d_in[5];
    const float* scaling = (const float*)d_in[6];
    float* out = (float*)d_out;

    unsigned short* Xe = (unsigned short*)d_ws;                    // 16384*2176*2 = 71.3 MB
    unsigned short* We = Xe + (size_t)NTOK * KEXT;                 // + 8.9 MB
    unsigned short* La = We + (size_t)D_OUT * KEXT;                // + 0.5 MB bf16 [128][2048]

    conv_prep<<<2336, 256, 0, stream>>>(x, weight, lora_a, lora_b, Xe, We, La);
    ext_gemm<<<NTOK / EBM, 256, 0, stream>>>(Xe, map, La, scaling);
    gemm_fused<<<(NTOK / BM) * (D_OUT / BN), 256, 0, stream>>>(Xe, We, bias, out);
}